// Round 3
// baseline (449.654 us; speedup 1.0000x reference)
//
#include <hip/hip_runtime.h>
#include <hip/hip_bf16.h>
#include <cstddef>

#define BB 16
#define SS 4096
#define DD 2048
#define AA 2048
#define NR 16          // rows per softmax chunk (one wave each)
#define CH 256         // chunks per batch = SS/NR
#define ACH 64         // a-chunks for vpart

__device__ inline unsigned int pk_bf16(float a, float b) {
  __hip_bfloat162 h2 = __float22bfloat162_rn(make_float2(a, b));
  return *reinterpret_cast<unsigned int*>(&h2);
}

// ---------------- kernel 1: hp[b,a] = hid[b,:]·W[a,:] + bias[a] ----------------
__global__ __launch_bounds__(256) void hp_kernel(
    const float* __restrict__ hid, const float* __restrict__ W,
    const float* __restrict__ bias, float* __restrict__ hp) {
  int gw   = (blockIdx.x * 256 + threadIdx.x) >> 6;  // a
  int lane = threadIdx.x & 63;
  int a = gw;
  const float4* Wr = reinterpret_cast<const float4*>(W + (size_t)a * DD);
  float acc[BB];
#pragma unroll
  for (int b = 0; b < BB; ++b) acc[b] = 0.f;
#pragma unroll
  for (int k = 0; k < 8; ++k) {
    float4 w4 = Wr[lane + 64 * k];
#pragma unroll
    for (int b = 0; b < BB; ++b) {
      float4 h4 = reinterpret_cast<const float4*>(hid + b * DD)[lane + 64 * k];
      acc[b] += w4.x * h4.x + w4.y * h4.y + w4.z * h4.z + w4.w * h4.w;
    }
  }
  float bi = bias[a];
#pragma unroll
  for (int b = 0; b < BB; ++b) {
    float s = acc[b];
#pragma unroll
    for (int off = 32; off; off >>= 1) s += __shfl_xor(s, off, 64);
    if (lane == 0) hp[b * AA + a] = s + bi;
  }
}

// ---------------- kernel 2: vpart[ac][b][d] = sum over a-chunk of hp[b,a]*W[a,d] ----------------
__global__ __launch_bounds__(256) void vpart_kernel(
    const float* __restrict__ hp, const float* __restrict__ W,
    float* __restrict__ vpart) {
  int t  = threadIdx.x;
  int ac = blockIdx.x & 63;
  int dc = blockIdx.x >> 6;
  int d0 = dc * 1024 + 4 * t;
  float4 acc[BB];
#pragma unroll
  for (int b = 0; b < BB; ++b) acc[b] = make_float4(0.f, 0.f, 0.f, 0.f);
  int abase = ac * 32;
  for (int i = 0; i < 32; ++i) {
    int a = abase + i;
    float4 w4 = *reinterpret_cast<const float4*>(W + (size_t)a * DD + d0);
#pragma unroll
    for (int b = 0; b < BB; ++b) {
      float h = hp[b * AA + a];  // wave-uniform -> scalar load
      acc[b].x += h * w4.x; acc[b].y += h * w4.y;
      acc[b].z += h * w4.z; acc[b].w += h * w4.w;
    }
  }
#pragma unroll
  for (int b = 0; b < BB; ++b)
    *reinterpret_cast<float4*>(vpart + (size_t)(ac * BB + b) * DD + d0) = acc[b];
}

// ---------------- kernel 3: c[b] = sum_a bias[a]*hp[b,a] ----------------
__global__ __launch_bounds__(256) void c_kernel(
    const float* __restrict__ hp, const float* __restrict__ bias,
    float* __restrict__ cvec) {
  int b = blockIdx.x, t = threadIdx.x;
  float s = 0.f;
  for (int i = t; i < AA; i += 256) s += bias[i] * hp[b * AA + i];
#pragma unroll
  for (int off = 32; off; off >>= 1) s += __shfl_xor(s, off, 64);
  __shared__ float red[4];
  if ((t & 63) == 0) red[t >> 6] = s;
  __syncthreads();
  if (t == 0) cvec[b] = red[0] + red[1] + red[2] + red[3];
}

// ---------------- kernel 4: v[b,d] = sum over achunks ----------------
__global__ __launch_bounds__(256) void reducev_kernel(
    const float* __restrict__ vpart, float* __restrict__ v) {
  int i = blockIdx.x * 256 + threadIdx.x;  // i = b*DD + d
  float s = 0.f;
#pragma unroll
  for (int c = 0; c < ACH; ++c) s += vpart[(size_t)c * (BB * DD) + i];
  v[i] = s;
}

// ---------------- kernel 5 (FUSED): one HBM pass over enc ----------------
// wave = (b, chunk of NR=16 rows). Per row: score = enc_row·v[b] + c[b]
// (exact, written), then online-softmax weighted accumulate into bf16 partial.
// Double-buffered row loads (eA/eB) keep VMEM busy through the shfl chain.
// v[b] reloaded from L1 per row (hot, shared by the whole block).
__global__ __launch_bounds__(256, 4) void fused_kernel(
    const float* __restrict__ enc, const float* __restrict__ v,
    const float* __restrict__ cvec, float* __restrict__ scores,
    float* __restrict__ mpart, float* __restrict__ lpart,
    unsigned int* __restrict__ ctxpart /* packed bf16x2 */) {
  int gw   = blockIdx.x * 4 + (threadIdx.x >> 6);  // 4096 waves
  int lane = threadIdx.x & 63;
  int b  = gw >> 8;        // CH=256 chunks per b
  int ch = gw & (CH - 1);
  const float4* vp = reinterpret_cast<const float4*>(v + b * DD);
  float cb = cvec[b];
  float4 acc[8];
#pragma unroll
  for (int k = 0; k < 8; ++k) acc[k] = make_float4(0.f, 0.f, 0.f, 0.f);
  float m = -1e30f, l = 0.f, myscore = 0.f;
  const float4* rowp = reinterpret_cast<const float4*>(
      enc + (size_t)(b * SS + ch * NR) * DD);  // 512 float4 per row
  float4 eA[8], eB[8];
#pragma unroll
  for (int k = 0; k < 8; ++k) eA[k] = rowp[lane + 64 * k];

#define STEP(CUR, NXT, R)                                                     \
  {                                                                           \
    int rn = ((R) + 1 < NR) ? (R) + 1 : (R);                                  \
    _Pragma("unroll")                                                         \
    for (int k = 0; k < 8; ++k)                                               \
      NXT[k] = rowp[(size_t)rn * 512 + lane + 64 * k];                        \
    float dot = 0.f;                                                          \
    _Pragma("unroll")                                                         \
    for (int k = 0; k < 8; ++k) {                                             \
      float4 vv = vp[lane + 64 * k];                                          \
      dot += CUR[k].x * vv.x + CUR[k].y * vv.y + CUR[k].z * vv.z +            \
             CUR[k].w * vv.w;                                                 \
    }                                                                         \
    _Pragma("unroll")                                                         \
    for (int off = 32; off; off >>= 1) dot += __shfl_xor(dot, off, 64);       \
    float score = dot + cb;                                                   \
    if (lane == (R)) myscore = score;                                         \
    float mnew  = fmaxf(m, score);                                            \
    float scale = __expf(m - mnew);                                           \
    float p     = __expf(score - mnew);                                       \
    l = l * scale + p;                                                        \
    _Pragma("unroll")                                                         \
    for (int k = 0; k < 8; ++k) {                                             \
      acc[k].x = acc[k].x * scale + p * CUR[k].x;                             \
      acc[k].y = acc[k].y * scale + p * CUR[k].y;                             \
      acc[k].z = acc[k].z * scale + p * CUR[k].z;                             \
      acc[k].w = acc[k].w * scale + p * CUR[k].w;                             \
    }                                                                         \
    m = mnew;                                                                 \
  }

#pragma unroll
  for (int rr = 0; rr < NR; rr += 2) {
    STEP(eA, eB, rr)
    STEP(eB, eA, rr + 1)
  }
#undef STEP

  if (lane < NR) scores[b * SS + ch * NR + lane] = myscore;
  if (lane == 0) { mpart[gw] = m; lpart[gw] = l; }
  uint2* cp = reinterpret_cast<uint2*>(ctxpart) + (size_t)gw * 512;
#pragma unroll
  for (int k = 0; k < 8; ++k) {
    uint2 u;
    u.x = pk_bf16(acc[k].x, acc[k].y);
    u.y = pk_bf16(acc[k].z, acc[k].w);
    cp[lane + 64 * k] = u;
  }
}

// ---------------- kernel 6: per-b combine weights ----------------
// wnorm[b,c] = exp(m_c - M_b) / L_b,  L_b = sum_c l_c * exp(m_c - M_b)
__global__ __launch_bounds__(256) void mstats_kernel(
    const float* __restrict__ mpart, const float* __restrict__ lpart,
    float* __restrict__ wnorm) {
  int b = blockIdx.x, t = threadIdx.x;  // t = chunk in [0,256)
  float mt = mpart[b * CH + t];
  float lt = lpart[b * CH + t];
  float M = mt;
#pragma unroll
  for (int off = 32; off; off >>= 1) M = fmaxf(M, __shfl_xor(M, off, 64));
  __shared__ float sm[4];
  if ((t & 63) == 0) sm[t >> 6] = M;
  __syncthreads();
  M = fmaxf(fmaxf(sm[0], sm[1]), fmaxf(sm[2], sm[3]));
  float w  = __expf(mt - M);
  float lw = lt * w;
#pragma unroll
  for (int off = 32; off; off >>= 1) lw += __shfl_xor(lw, off, 64);
  __shared__ float sl[4];
  if ((t & 63) == 0) sl[t >> 6] = lw;
  __syncthreads();
  float L = sl[0] + sl[1] + sl[2] + sl[3];
  wnorm[b * CH + t] = w / L;
}

// ---------------- kernel 7: weighted partial combine (stage 1) ----------------
// grid (b, g=0..15): part2[b,g,:] = sum_{c in g*16..g*16+15} wnorm[b,c]*ctxpart[b,c,:]
__global__ __launch_bounds__(256) void combine1_kernel(
    const unsigned int* __restrict__ ctxpart, const float* __restrict__ wnorm,
    float* __restrict__ part2) {
  int b = blockIdx.x >> 4;
  int g = blockIdx.x & 15;
  int t = threadIdx.x;   // covers bf16 cols [8t, 8t+8)
  float a0 = 0.f, a1 = 0.f, a2 = 0.f, a3 = 0.f;
  float a4 = 0.f, a5 = 0.f, a6 = 0.f, a7 = 0.f;
  for (int i = 0; i < 16; ++i) {
    int c = g * 16 + i;
    float w = wnorm[b * CH + c];  // wave-uniform
    const uint4* p = reinterpret_cast<const uint4*>(
        ctxpart + (size_t)(b * CH + c) * (DD / 2));
    uint4 q = p[t];
    a0 += w * __uint_as_float(q.x << 16);
    a1 += w * __uint_as_float(q.x & 0xffff0000u);
    a2 += w * __uint_as_float(q.y << 16);
    a3 += w * __uint_as_float(q.y & 0xffff0000u);
    a4 += w * __uint_as_float(q.z << 16);
    a5 += w * __uint_as_float(q.z & 0xffff0000u);
    a6 += w * __uint_as_float(q.w << 16);
    a7 += w * __uint_as_float(q.w & 0xffff0000u);
  }
  float4* o = reinterpret_cast<float4*>(part2 + (size_t)(b * 16 + g) * DD + 8 * t);
  o[0] = make_float4(a0, a1, a2, a3);
  o[1] = make_float4(a4, a5, a6, a7);
}

// ---------------- kernel 8: final ctx reduce (stage 2) ----------------
__global__ __launch_bounds__(256) void combine2_kernel(
    const float* __restrict__ part2, float* __restrict__ ctx) {
  int i = blockIdx.x * 256 + threadIdx.x;  // [0, BB*DD)
  int b = i >> 11;
  int d = i & 2047;
  float s = 0.f;
#pragma unroll
  for (int g = 0; g < 16; ++g) s += part2[(size_t)(b * 16 + g) * DD + d];
  ctx[i] = s;
}

extern "C" void kernel_launch(void* const* d_in, const int* in_sizes, int n_in,
                              void* d_out, int out_size, void* d_ws, size_t ws_size,
                              hipStream_t stream) {
  const float* enc  = (const float*)d_in[0];  // [B,S,D]
  const float* hid  = (const float*)d_in[1];  // [B,D]
  const float* W    = (const float*)d_in[2];  // [A,D]
  const float* bias = (const float*)d_in[3];  // [A]

  float* out_scores = (float*)d_out;            // [B,S]
  float* out_ctx    = (float*)d_out + BB * SS;  // [B,D]

  float* ws    = (float*)d_ws;
  float* hp    = ws;                        // B*A        = 32768 f
  float* vpart = hp + BB * AA;              // ACH*B*D    = 2097152 f
  float* v     = vpart + ACH * BB * DD;     // B*D        = 32768 f
  float* cvec  = v + BB * DD;               // B          = 16 f
  float* mpart = cvec + BB;                 // B*CH       = 4096 f
  float* lpart = mpart + BB * CH;           // B*CH       = 4096 f
  float* wnorm = lpart + BB * CH;           // B*CH       = 4096 f
  unsigned int* ctxp = (unsigned int*)(wnorm + BB * CH);  // B*CH*D bf16 = 16 MB
  float* part2 = (float*)(ctxp + (size_t)BB * CH * DD / 2);  // B*16*D f32 = 2 MB
  // total ~27.5 MB

  hipLaunchKernelGGL(hp_kernel,      dim3(512),  dim3(256), 0, stream, hid, W, bias, hp);
  hipLaunchKernelGGL(vpart_kernel,   dim3(128),  dim3(256), 0, stream, hp, W, vpart);
  hipLaunchKernelGGL(c_kernel,       dim3(16),   dim3(256), 0, stream, hp, bias, cvec);
  hipLaunchKernelGGL(reducev_kernel, dim3(128),  dim3(256), 0, stream, vpart, v);
  hipLaunchKernelGGL(fused_kernel,   dim3(1024), dim3(256), 0, stream,
                     enc, v, cvec, out_scores, mpart, lpart, ctxp);
  hipLaunchKernelGGL(mstats_kernel,  dim3(16),   dim3(256), 0, stream, mpart, lpart, wnorm);
  hipLaunchKernelGGL(combine1_kernel, dim3(256), dim3(256), 0, stream, ctxp, wnorm, part2);
  hipLaunchKernelGGL(combine2_kernel, dim3(128), dim3(256), 0, stream, part2, out_ctx);
}

// Round 4
// 198.454 us; speedup vs baseline: 2.2658x; 2.2658x over previous
//
#include <hip/hip_runtime.h>
#include <hip/hip_bf16.h>
#include <cstddef>

#define BB 16
#define SS 4096
#define DD 2048
#define AA 2048
#define NR 16          // rows per softmax chunk (one wave each)
#define CH 256         // chunks per batch = SS/NR
#define ACH 64         // a-chunks for vpart

__device__ inline unsigned int pk_bf16(float a, float b) {
  __hip_bfloat162 h2 = __float22bfloat162_rn(make_float2(a, b));
  return *reinterpret_cast<unsigned int*>(&h2);
}

// ---------------- kernel 1: hp[b,a] = hid[b,:]·W[a,:] + bias[a] ----------------
__global__ __launch_bounds__(256) void hp_kernel(
    const float* __restrict__ hid, const float* __restrict__ W,
    const float* __restrict__ bias, float* __restrict__ hp) {
  int gw   = (blockIdx.x * 256 + threadIdx.x) >> 6;  // a
  int lane = threadIdx.x & 63;
  int a = gw;
  const float4* Wr = reinterpret_cast<const float4*>(W + (size_t)a * DD);
  float acc[BB];
#pragma unroll
  for (int b = 0; b < BB; ++b) acc[b] = 0.f;
#pragma unroll
  for (int k = 0; k < 8; ++k) {
    float4 w4 = Wr[lane + 64 * k];
#pragma unroll
    for (int b = 0; b < BB; ++b) {
      float4 h4 = reinterpret_cast<const float4*>(hid + b * DD)[lane + 64 * k];
      acc[b] += w4.x * h4.x + w4.y * h4.y + w4.z * h4.z + w4.w * h4.w;
    }
  }
  float bi = bias[a];
#pragma unroll
  for (int b = 0; b < BB; ++b) {
    float s = acc[b];
#pragma unroll
    for (int off = 32; off; off >>= 1) s += __shfl_xor(s, off, 64);
    if (lane == 0) hp[b * AA + a] = s + bi;
  }
}

// ---------------- kernel 2: vpart[ac][b][d] = sum over a-chunk of hp[b,a]*W[a,d] ----------------
__global__ __launch_bounds__(256) void vpart_kernel(
    const float* __restrict__ hp, const float* __restrict__ W,
    float* __restrict__ vpart) {
  int t  = threadIdx.x;
  int ac = blockIdx.x & 63;
  int dc = blockIdx.x >> 6;
  int d0 = dc * 1024 + 4 * t;
  float4 acc[BB];
#pragma unroll
  for (int b = 0; b < BB; ++b) acc[b] = make_float4(0.f, 0.f, 0.f, 0.f);
  int abase = ac * 32;
  for (int i = 0; i < 32; ++i) {
    int a = abase + i;
    float4 w4 = *reinterpret_cast<const float4*>(W + (size_t)a * DD + d0);
#pragma unroll
    for (int b = 0; b < BB; ++b) {
      float h = hp[b * AA + a];  // wave-uniform -> scalar load
      acc[b].x += h * w4.x; acc[b].y += h * w4.y;
      acc[b].z += h * w4.z; acc[b].w += h * w4.w;
    }
  }
#pragma unroll
  for (int b = 0; b < BB; ++b)
    *reinterpret_cast<float4*>(vpart + (size_t)(ac * BB + b) * DD + d0) = acc[b];
}

// ---------------- kernel 3 (merged): v reduce + c[b] ----------------
// blocks 0..127: v[i] = sum over achunks of vpart; blocks 128..143: c[b].
__global__ __launch_bounds__(256) void finalize_kernel(
    const float* __restrict__ vpart, const float* __restrict__ hp,
    const float* __restrict__ bias, float* __restrict__ v,
    float* __restrict__ cvec) {
  if (blockIdx.x < 128) {
    int i = blockIdx.x * 256 + threadIdx.x;  // i = b*DD + d
    float s = 0.f;
#pragma unroll
    for (int c = 0; c < ACH; ++c) s += vpart[(size_t)c * (BB * DD) + i];
    v[i] = s;
  } else {
    int b = blockIdx.x - 128;
    int t = threadIdx.x;
    float s = 0.f;
    for (int i = t; i < AA; i += 256) s += bias[i] * hp[b * AA + i];
#pragma unroll
    for (int off = 32; off; off >>= 1) s += __shfl_xor(s, off, 64);
    __shared__ float red[4];
    if ((t & 63) == 0) red[t >> 6] = s;
    __syncthreads();
    if (t == 0) cvec[b] = red[0] + red[1] + red[2] + red[3];
  }
}

// ---------------- kernel 4 (FUSED): one HBM pass over enc ----------------
// wave = (b, chunk of NR=16 rows). score = enc_row·v[b] + c[b] (exact, written),
// then deferred-rescale online-softmax accumulate into bf16 partial.
// No v register cache (reload from L1 — block shares one b), no double buffer:
// keep VGPRs ~90 so 4+ waves/SIMD hide latency via TLP.
__global__ __launch_bounds__(256) void fused_kernel(
    const float* __restrict__ enc, const float* __restrict__ v,
    const float* __restrict__ cvec, float* __restrict__ scores,
    float* __restrict__ mpart, float* __restrict__ lpart,
    unsigned int* __restrict__ ctxpart /* packed bf16x2 */) {
  int gw   = blockIdx.x * 4 + (threadIdx.x >> 6);  // 4096 waves
  int lane = threadIdx.x & 63;
  int b  = gw >> 8;        // CH=256 chunks per b
  int ch = gw & (CH - 1);
  const float4* vp = reinterpret_cast<const float4*>(v + (size_t)b * DD);
  float cb = cvec[b];
  float4 acc[8];
#pragma unroll
  for (int k = 0; k < 8; ++k) acc[k] = make_float4(0.f, 0.f, 0.f, 0.f);
  float m_s = -1e30f;   // exp base (deferred max)
  float l = 0.f, myscore = 0.f;
  const float4* rowp = reinterpret_cast<const float4*>(
      enc + (size_t)(b * SS + ch * NR) * DD);  // 512 float4 per row

#pragma unroll
  for (int r = 0; r < NR; ++r) {
    float4 e[8];
#pragma unroll
    for (int k = 0; k < 8; ++k) e[k] = rowp[(size_t)r * 512 + lane + 64 * k];
    float dot = 0.f;
#pragma unroll
    for (int k = 0; k < 8; ++k) {
      float4 vv = vp[lane + 64 * k];
      dot += e[k].x * vv.x + e[k].y * vv.y + e[k].z * vv.z + e[k].w * vv.w;
    }
#pragma unroll
    for (int off = 32; off; off >>= 1) dot += __shfl_xor(dot, off, 64);
    float score = dot + cb;          // wave-uniform
    if (lane == r) myscore = score;
    if (score > m_s + 40.f) {        // uniform branch, taken rarely
      float rs = __expf(m_s - score);  // 0 on first row (underflow) — acc is 0 anyway
      l *= rs;
#pragma unroll
      for (int k = 0; k < 8; ++k) {
        acc[k].x *= rs; acc[k].y *= rs; acc[k].z *= rs; acc[k].w *= rs;
      }
      m_s = score;
    }
    float p = __expf(score - m_s);   // <= e^40, f32-safe
    l += p;
#pragma unroll
    for (int k = 0; k < 8; ++k) {
      acc[k].x += p * e[k].x;
      acc[k].y += p * e[k].y;
      acc[k].z += p * e[k].z;
      acc[k].w += p * e[k].w;
    }
  }

  if (lane < NR) scores[b * SS + ch * NR + lane] = myscore;
  if (lane == 0) { mpart[gw] = m_s; lpart[gw] = l; }
  uint2* cp = reinterpret_cast<uint2*>(ctxpart) + (size_t)gw * 512;
#pragma unroll
  for (int k = 0; k < 8; ++k) {
    uint2 u;
    u.x = pk_bf16(acc[k].x, acc[k].y);
    u.y = pk_bf16(acc[k].z, acc[k].w);
    cp[lane + 64 * k] = u;
  }
}

// ---------------- kernel 5 (merged epilogue): weights + weighted combine ----------------
// block = (b, dslice of 256 cols). Recompute per-b weights in LDS, then
// ctx[b, dslice] = sum_c w[c] * ctxpart[b,c,dslice]. Exact sequential f32 sum.
__global__ __launch_bounds__(256) void epilogue_kernel(
    const float* __restrict__ mpart, const float* __restrict__ lpart,
    const unsigned int* __restrict__ ctxpart, float* __restrict__ ctx) {
  int b  = blockIdx.x >> 3;
  int ds = blockIdx.x & 7;
  int t  = threadIdx.x;   // t in [0,256) — one chunk for stage 1, one col for stage 2
  __shared__ float wsm[CH];
  __shared__ float redm[4], redl[4];
  // stage 1: per-b combine weights  w[c] = exp(m_c - M) / L
  float mt = mpart[b * CH + t];
  float lt = lpart[b * CH + t];
  float M = mt;
#pragma unroll
  for (int off = 32; off; off >>= 1) M = fmaxf(M, __shfl_xor(M, off, 64));
  if ((t & 63) == 0) redm[t >> 6] = M;
  __syncthreads();
  M = fmaxf(fmaxf(redm[0], redm[1]), fmaxf(redm[2], redm[3]));
  float w  = __expf(mt - M);
  float lw = lt * w;
#pragma unroll
  for (int off = 32; off; off >>= 1) lw += __shfl_xor(lw, off, 64);
  if ((t & 63) == 0) redl[t >> 6] = lw;
  __syncthreads();
  float L = redl[0] + redl[1] + redl[2] + redl[3];
  wsm[t] = w / L;
  __syncthreads();
  // stage 2: thread owns column d = ds*256 + t (bf16 stored, pairs packed)
  int du = ds * 128 + (t >> 1);       // uint index within a chunk row
  bool hi = (t & 1);
  float acc = 0.f;
  const unsigned int* base = ctxpart + (size_t)(b * CH) * (DD / 2) + du;
  for (int c = 0; c < CH; ++c) {
    unsigned int u = base[(size_t)c * (DD / 2)];
    float e = __uint_as_float(hi ? (u & 0xffff0000u) : (u << 16));
    acc += wsm[c] * e;
  }
  ctx[b * DD + ds * 256 + t] = acc;
}

extern "C" void kernel_launch(void* const* d_in, const int* in_sizes, int n_in,
                              void* d_out, int out_size, void* d_ws, size_t ws_size,
                              hipStream_t stream) {
  const float* enc  = (const float*)d_in[0];  // [B,S,D]
  const float* hid  = (const float*)d_in[1];  // [B,D]
  const float* W    = (const float*)d_in[2];  // [A,D]
  const float* bias = (const float*)d_in[3];  // [A]

  float* out_scores = (float*)d_out;            // [B,S]
  float* out_ctx    = (float*)d_out + BB * SS;  // [B,D]

  float* ws    = (float*)d_ws;
  float* hp    = ws;                        // B*A        = 32768 f
  float* vpart = hp + BB * AA;              // ACH*B*D    = 2097152 f
  float* v     = vpart + ACH * BB * DD;     // B*D        = 32768 f
  float* cvec  = v + BB * DD;               // B          = 16 f
  float* mpart = cvec + BB;                 // B*CH       = 4096 f
  float* lpart = mpart + BB * CH;           // B*CH       = 4096 f
  unsigned int* ctxp = (unsigned int*)(lpart + BB * CH);  // B*CH*D bf16 = 16 MB
  // total ~25 MB

  hipLaunchKernelGGL(hp_kernel,       dim3(512),  dim3(256), 0, stream, hid, W, bias, hp);
  hipLaunchKernelGGL(vpart_kernel,    dim3(128),  dim3(256), 0, stream, hp, W, vpart);
  hipLaunchKernelGGL(finalize_kernel, dim3(144),  dim3(256), 0, stream, vpart, hp, bias, v, cvec);
  hipLaunchKernelGGL(fused_kernel,    dim3(1024), dim3(256), 0, stream,
                     enc, v, cvec, out_scores, mpart, lpart, ctxp);
  hipLaunchKernelGGL(epilogue_kernel, dim3(128),  dim3(256), 0, stream,
                     mpart, lpart, ctxp, out_ctx);
}